// Round 2
// baseline (636.155 us; speedup 1.0000x reference)
//
#include <hip/hip_runtime.h>
#include <math.h>

#define CS 256
#define CZ 128
#define HEADS 8
#define DH 32
#define SDIM 128
#define RDIM 256
#define MROWS (SDIM*RDIM)   // 32768
#define ZROWS (RDIM*RDIM)   // 65536
#define EPSF 1e-5f
#define LOG2E 1.44269504088896340736f

__device__ __forceinline__ float waveReduceSum(float v) {
    #pragma unroll
    for (int off = 32; off > 0; off >>= 1) v += __shfl_xor(v, off, 64);
    return v;
}

// ---------------- LayerNorm of s: one wave per row of 256 ----------------
__global__ __launch_bounds__(256) void ln_s_kernel(const float* __restrict__ s,
        const float* __restrict__ w, const float* __restrict__ b,
        float* __restrict__ sn) {
    int wid = threadIdx.x >> 6;
    int lane = threadIdx.x & 63;
    int row = blockIdx.x * 4 + wid;              // < 32768
    const float4 v = ((const float4*)(s + (size_t)row * CS))[lane];
    float sum = waveReduceSum(v.x + v.y + v.z + v.w);
    float sq  = waveReduceSum(v.x*v.x + v.y*v.y + v.z*v.z + v.w*v.w);
    float mean = sum * (1.f/CS);
    float var  = sq * (1.f/CS) - mean*mean;
    float rstd = rsqrtf(var + EPSF);
    const float4 wv = ((const float4*)w)[lane];
    const float4 bv = ((const float4*)b)[lane];
    float4 o;
    o.x = (v.x-mean)*rstd*wv.x + bv.x;
    o.y = (v.y-mean)*rstd*wv.y + bv.y;
    o.z = (v.z-mean)*rstd*wv.z + bv.z;
    o.w = (v.w-mean)*rstd*wv.w + bv.w;
    ((float4*)(sn + (size_t)row * CS))[lane] = o;
}

// ------- LayerNorm of z + pair bias: one wave per (q,k) row of 128 -------
// writes pbT[h][k][q]  (transposed so attention reads coalesced in q)
__global__ __launch_bounds__(256) void ln_z_pb_kernel(const float* __restrict__ z,
        const float* __restrict__ w, const float* __restrict__ b,
        const float* __restrict__ wz, float* __restrict__ pbT) {
    int wid = threadIdx.x >> 6;
    int lane = threadIdx.x & 63;
    int row = blockIdx.x * 4 + wid;              // row = q*256 + k, < 65536
    const float2 v = ((const float2*)(z + (size_t)row * CZ))[lane];
    float sum = waveReduceSum(v.x + v.y);
    float sq  = waveReduceSum(v.x*v.x + v.y*v.y);
    float mean = sum * (1.f/CZ);
    float var  = sq * (1.f/CZ) - mean*mean;
    float rstd = rsqrtf(var + EPSF);
    const float2 wv = ((const float2*)w)[lane];
    const float2 bv = ((const float2*)b)[lane];
    float n0 = (v.x-mean)*rstd*wv.x + bv.x;
    float n1 = (v.y-mean)*rstd*wv.y + bv.y;
    const float* wz0 = wz + (size_t)(lane*2) * HEADS;   // wz: [128][8]
    float ph[8];
    #pragma unroll
    for (int h = 0; h < 8; h++) ph[h] = n0*wz0[h] + n1*wz0[HEADS + h];
    #pragma unroll
    for (int h = 0; h < 8; h++) ph[h] = waveReduceSum(ph[h]);
    if (lane == 0) {
        int q = row >> 8, k = row & 255;
        #pragma unroll
        for (int h = 0; h < 8; h++)
            pbT[(size_t)h*ZROWS + (size_t)k*RDIM + q] = ph[h];
    }
}

// ------------- QKVG projection GEMM: M=32768, K=256, N=1024 --------------
// A = sn [M,256]; B = [wq | wk | wv | wg] each [256,256]
// q/k/v written [S,H,R,D]; g written [M,256] = sigmoid(. + bg)
__global__ __launch_bounds__(256) void qkvg_kernel(const float* __restrict__ A,
        const float* __restrict__ wq, const float* __restrict__ wk,
        const float* __restrict__ wv, const float* __restrict__ wg,
        const float* __restrict__ bg,
        float* __restrict__ qo, float* __restrict__ ko,
        float* __restrict__ vo, float* __restrict__ go) {
    __shared__ float As[16][64];   // transposed A tile: As[k][r]
    __shared__ float Bs[16][64];
    const int m0 = blockIdx.x * 64;
    const int ncol = blockIdx.y * 64;            // 0..1023
    const int seg = ncol >> 8;
    const float* W = (seg == 0) ? wq : (seg == 1) ? wk : (seg == 2) ? wv : wg;
    const int c0 = ncol & 255;
    const int tid = threadIdx.x;
    const int tx = tid & 15, ty = tid >> 4;
    const int lr = tid >> 2;                     // A-load row 0..63
    const int lk4 = (tid & 3) * 4;               // A-load k offset
    const int bx = tid & 63;
    float acc[4][4] = {};
    for (int k0 = 0; k0 < 256; k0 += 16) {
        float4 av = *(const float4*)(A + (size_t)(m0 + lr)*CS + k0 + lk4);
        As[lk4+0][lr] = av.x; As[lk4+1][lr] = av.y;
        As[lk4+2][lr] = av.z; As[lk4+3][lr] = av.w;
        #pragma unroll
        for (int i = 0; i < 4; i++) {
            int kk = (tid >> 6) + i*4;
            Bs[kk][bx] = W[(size_t)(k0 + kk)*CS + c0 + bx];
        }
        __syncthreads();
        #pragma unroll
        for (int kk = 0; kk < 16; kk++) {
            float4 a4 = *(const float4*)&As[kk][ty*4];
            float4 b4 = *(const float4*)&Bs[kk][tx*4];
            float av_[4] = {a4.x, a4.y, a4.z, a4.w};
            float bv_[4] = {b4.x, b4.y, b4.z, b4.w};
            #pragma unroll
            for (int i = 0; i < 4; i++)
                #pragma unroll
                for (int j = 0; j < 4; j++)
                    acc[i][j] += av_[i] * bv_[j];
        }
        __syncthreads();
    }
    #pragma unroll
    for (int i = 0; i < 4; i++) {
        int m = m0 + ty*4 + i;
        int ss = m >> 8, rr = m & 255;
        #pragma unroll
        for (int j = 0; j < 4; j++) {
            int lc = c0 + tx*4 + j;              // col within segment, 0..255
            float val = acc[i][j];
            if (seg == 0) {
                int h = lc >> 5, d = lc & 31;
                qo[(((size_t)ss*HEADS + h)*RDIM + rr)*DH + d] = val * 0.17677669529663687f;
            } else if (seg == 1) {
                int h = lc >> 5, d = lc & 31;
                ko[(((size_t)ss*HEADS + h)*RDIM + rr)*DH + d] = val;
            } else if (seg == 2) {
                int h = lc >> 5, d = lc & 31;
                vo[(((size_t)ss*HEADS + h)*RDIM + rr)*DH + d] = val;
            } else {
                float x = val + bg[lc];
                go[(size_t)m*CS + lc] = 1.f / (1.f + expf(-x));
            }
        }
    }
}

// ---------------- attention: one block per (s,h), flash-style ------------
__global__ __launch_bounds__(256) void attn_kernel(const float* __restrict__ q,
        const float* __restrict__ k, const float* __restrict__ v,
        const float* __restrict__ pbT, const float* __restrict__ mask,
        float* __restrict__ o) {
    __shared__ float klds[256][32];
    __shared__ float vlds[256][32];
    const int sh = blockIdx.x;                   // s*8 + h
    const int ss = sh >> 3, h = sh & 7;
    const int tid = threadIdx.x;                 // query row
    const float* kp = k + (size_t)sh * 8192;
    const float* vp = v + (size_t)sh * 8192;
    #pragma unroll
    for (int i = 0; i < 8; i++) {
        int idx = tid + i*256;                   // float4 index, 0..2047
        ((float4*)&klds[0][0])[idx] = ((const float4*)kp)[idx];
        ((float4*)&vlds[0][0])[idx] = ((const float4*)vp)[idx];
    }
    float qr[32];
    {
        const float4* qp = (const float4*)(q + (size_t)sh*8192 + (size_t)tid*DH);
        #pragma unroll
        for (int i = 0; i < 8; i++) {
            float4 t = qp[i];
            qr[i*4+0]=t.x; qr[i*4+1]=t.y; qr[i*4+2]=t.z; qr[i*4+3]=t.w;
        }
    }
    __syncthreads();
    const float* pb = pbT + (size_t)h*ZROWS + tid;   // + kk*256
    const float* mrow = mask + (size_t)ss*RDIM;
    float mx = -INFINITY, l = 0.f;
    float oacc[32] = {};
    for (int kk = 0; kk < 256; kk++) {
        float dot = 0.f;
        #pragma unroll
        for (int d4 = 0; d4 < 8; d4++) {
            float4 kv = *(const float4*)&klds[kk][d4*4];
            dot += qr[d4*4+0]*kv.x + qr[d4*4+1]*kv.y
                 + qr[d4*4+2]*kv.z + qr[d4*4+3]*kv.w;
        }
        float logit = dot + 1e9f*(mrow[kk] - 1.f) + pb[(size_t)kk*RDIM];
        if (logit > mx) {
            float c = exp2f((mx - logit) * LOG2E);
            l *= c;
            #pragma unroll
            for (int d = 0; d < 32; d++) oacc[d] *= c;
            mx = logit;
        }
        float p = exp2f((logit - mx) * LOG2E);
        l += p;
        #pragma unroll
        for (int d4 = 0; d4 < 8; d4++) {
            float4 vv = *(const float4*)&vlds[kk][d4*4];
            oacc[d4*4+0] += p*vv.x; oacc[d4*4+1] += p*vv.y;
            oacc[d4*4+2] += p*vv.z; oacc[d4*4+3] += p*vv.w;
        }
    }
    float inv = 1.f / l;
    float4* op = (float4*)(o + ((size_t)ss*RDIM + tid)*CS + h*DH);
    #pragma unroll
    for (int d4 = 0; d4 < 8; d4++) {
        float4 t;
        t.x = oacc[d4*4+0]*inv; t.y = oacc[d4*4+1]*inv;
        t.z = oacc[d4*4+2]*inv; t.w = oacc[d4*4+3]*inv;
        op[d4] = t;
    }
}

// ------------- output projection: out = (o .* g) @ wo + bo ---------------
__global__ __launch_bounds__(256) void outproj_kernel(const float* __restrict__ o,
        const float* __restrict__ g, const float* __restrict__ wo,
        const float* __restrict__ bo, float* __restrict__ out) {
    __shared__ float As[16][64];
    __shared__ float Bs[16][64];
    const int m0 = blockIdx.x * 64;
    const int c0 = blockIdx.y * 64;              // 0..255
    const int tid = threadIdx.x;
    const int tx = tid & 15, ty = tid >> 4;
    const int lr = tid >> 2;
    const int lk4 = (tid & 3) * 4;
    const int bx = tid & 63;
    float acc[4][4] = {};
    for (int k0 = 0; k0 < 256; k0 += 16) {
        float4 av = *(const float4*)(o + (size_t)(m0 + lr)*CS + k0 + lk4);
        float4 gv = *(const float4*)(g + (size_t)(m0 + lr)*CS + k0 + lk4);
        As[lk4+0][lr] = av.x*gv.x; As[lk4+1][lr] = av.y*gv.y;
        As[lk4+2][lr] = av.z*gv.z; As[lk4+3][lr] = av.w*gv.w;
        #pragma unroll
        for (int i = 0; i < 4; i++) {
            int kk = (tid >> 6) + i*4;
            Bs[kk][bx] = wo[(size_t)(k0 + kk)*CS + c0 + bx];
        }
        __syncthreads();
        #pragma unroll
        for (int kk = 0; kk < 16; kk++) {
            float4 a4 = *(const float4*)&As[kk][ty*4];
            float4 b4 = *(const float4*)&Bs[kk][tx*4];
            float av_[4] = {a4.x, a4.y, a4.z, a4.w};
            float bv_[4] = {b4.x, b4.y, b4.z, b4.w};
            #pragma unroll
            for (int i = 0; i < 4; i++)
                #pragma unroll
                for (int j = 0; j < 4; j++)
                    acc[i][j] += av_[i] * bv_[j];
        }
        __syncthreads();
    }
    #pragma unroll
    for (int i = 0; i < 4; i++) {
        int m = m0 + ty*4 + i;
        #pragma unroll
        for (int j = 0; j < 4; j++) {
            int c = c0 + tx*4 + j;
            out[(size_t)m*CS + c] = acc[i][j] + bo[c];
        }
    }
}

extern "C" void kernel_launch(void* const* d_in, const int* in_sizes, int n_in,
                              void* d_out, int out_size, void* d_ws, size_t ws_size,
                              hipStream_t stream) {
    const float* s      = (const float*)d_in[0];
    const float* z      = (const float*)d_in[1];
    const float* mask   = (const float*)d_in[2];
    const float* ln_s_w = (const float*)d_in[3];
    const float* ln_s_b = (const float*)d_in[4];
    const float* ln_z_w = (const float*)d_in[5];
    const float* ln_z_b = (const float*)d_in[6];
    const float* w_z    = (const float*)d_in[7];
    const float* w_q    = (const float*)d_in[8];
    const float* w_k    = (const float*)d_in[9];
    const float* w_v    = (const float*)d_in[10];
    const float* w_g    = (const float*)d_in[11];
    const float* b_g    = (const float*)d_in[12];
    const float* w_o    = (const float*)d_in[13];
    const float* b_o    = (const float*)d_in[14];
    float* out = (float*)d_out;
    float* ws  = (float*)d_ws;

    // Sizes (floats): q/k/v are [S,H,R,D] = 128*8*256*32 = 8388608 EACH
    // (round-1 bug: had 1048576 = M*D, dropping H -> massive overlap races)
    float* sn  = ws;                       // 8388608 (aliased by o; sn dead after qkvg)
    float* o   = ws;
    float* pbT = ws + 8388608;             // 524288
    float* qb  = pbT + 524288;             // 8388608
    float* kb  = qb + 8388608;             // 8388608
    float* vb  = kb + 8388608;             // 8388608
    float* gb  = vb + 8388608;             // 8388608
    // total = 42467328 floats = 169.9 MB of d_ws

    ln_s_kernel<<<MROWS/4, 256, 0, stream>>>(s, ln_s_w, ln_s_b, sn);
    ln_z_pb_kernel<<<ZROWS/4, 256, 0, stream>>>(z, ln_z_w, ln_z_b, w_z, pbT);
    qkvg_kernel<<<dim3(MROWS/64, 16), 256, 0, stream>>>(sn, w_q, w_k, w_v, w_g, b_g,
                                                        qb, kb, vb, gb);
    attn_kernel<<<SDIM*HEADS, 256, 0, stream>>>(qb, kb, vb, pbT, mask, o);
    outproj_kernel<<<dim3(MROWS/64, 4), 256, 0, stream>>>(o, gb, w_o, b_o, out);
}

// Round 4
// 485.443 us; speedup vs baseline: 1.3105x; 1.3105x over previous
//
#include <hip/hip_runtime.h>
#include <math.h>

#define CS 256
#define CZ 128
#define HEADS 8
#define DH 32
#define SDIM 128
#define RDIM 256
#define MROWS (SDIM*RDIM)   // 32768
#define ZROWS (RDIM*RDIM)   // 65536
#define EPSF 1e-5f
#define LOG2E 1.44269504088896340736f

typedef __attribute__((ext_vector_type(8))) short short8_t;   // 8 bf16 (4 VGPRs)
typedef __attribute__((ext_vector_type(4))) float f32x4;

__device__ __forceinline__ float waveReduceSum(float v) {
    #pragma unroll
    for (int off = 32; off > 0; off >>= 1) v += __shfl_xor(v, off, 64);
    return v;
}

__device__ __forceinline__ unsigned short f2bf(float f) {
    unsigned u = __float_as_uint(f);
    unsigned r = (u + 0x7fffu + ((u >> 16) & 1u)) >> 16;   // RNE
    return (unsigned short)r;
}

// ---------------- LayerNorm of s: one wave per row of 256 ----------------
__global__ __launch_bounds__(256) void ln_s_kernel(const float* __restrict__ s,
        const float* __restrict__ w, const float* __restrict__ b,
        float* __restrict__ sn) {
    int wid = threadIdx.x >> 6;
    int lane = threadIdx.x & 63;
    int row = blockIdx.x * 4 + wid;              // < 32768
    const float4 v = ((const float4*)(s + (size_t)row * CS))[lane];
    float sum = waveReduceSum(v.x + v.y + v.z + v.w);
    float sq  = waveReduceSum(v.x*v.x + v.y*v.y + v.z*v.z + v.w*v.w);
    float mean = sum * (1.f/CS);
    float var  = sq * (1.f/CS) - mean*mean;
    float rstd = rsqrtf(var + EPSF);
    const float4 wv = ((const float4*)w)[lane];
    const float4 bv = ((const float4*)b)[lane];
    float4 o;
    o.x = (v.x-mean)*rstd*wv.x + bv.x;
    o.y = (v.y-mean)*rstd*wv.y + bv.y;
    o.z = (v.z-mean)*rstd*wv.z + bv.z;
    o.w = (v.w-mean)*rstd*wv.w + bv.w;
    ((float4*)(sn + (size_t)row * CS))[lane] = o;
}

// ------- LayerNorm of z + pair bias: one wave per (q,k) row of 128 -------
// writes pb[h][q][k]  (natural order: attn MFMA C-layout reads coalesce)
__global__ __launch_bounds__(256) void ln_z_pb_kernel(const float* __restrict__ z,
        const float* __restrict__ w, const float* __restrict__ b,
        const float* __restrict__ wz, float* __restrict__ pb) {
    int wid = threadIdx.x >> 6;
    int lane = threadIdx.x & 63;
    int row = blockIdx.x * 4 + wid;              // row = q*256 + k, < 65536
    const float2 v = ((const float2*)(z + (size_t)row * CZ))[lane];
    float sum = waveReduceSum(v.x + v.y);
    float sq  = waveReduceSum(v.x*v.x + v.y*v.y);
    float mean = sum * (1.f/CZ);
    float var  = sq * (1.f/CZ) - mean*mean;
    float rstd = rsqrtf(var + EPSF);
    const float2 wv = ((const float2*)w)[lane];
    const float2 bv = ((const float2*)b)[lane];
    float n0 = (v.x-mean)*rstd*wv.x + bv.x;
    float n1 = (v.y-mean)*rstd*wv.y + bv.y;
    const float* wz0 = wz + (size_t)(lane*2) * HEADS;   // wz: [128][8]
    float ph[8];
    #pragma unroll
    for (int h = 0; h < 8; h++) ph[h] = n0*wz0[h] + n1*wz0[HEADS + h];
    #pragma unroll
    for (int h = 0; h < 8; h++) ph[h] = waveReduceSum(ph[h]);
    if (lane == 0) {
        #pragma unroll
        for (int h = 0; h < 8; h++)
            pb[(size_t)h*ZROWS + row] = ph[h];   // [h][q][k]
    }
}

// ------------- QKVG projection GEMM: M=32768, K=256, N=1024 --------------
__global__ __launch_bounds__(256) void qkvg_kernel(const float* __restrict__ A,
        const float* __restrict__ wq, const float* __restrict__ wk,
        const float* __restrict__ wv, const float* __restrict__ wg,
        const float* __restrict__ bg,
        float* __restrict__ qo, float* __restrict__ ko,
        float* __restrict__ vo, float* __restrict__ go) {
    __shared__ float As[16][64];   // transposed A tile: As[k][r]
    __shared__ float Bs[16][64];
    const int m0 = blockIdx.x * 64;
    const int ncol = blockIdx.y * 64;            // 0..1023
    const int seg = ncol >> 8;
    const float* W = (seg == 0) ? wq : (seg == 1) ? wk : (seg == 2) ? wv : wg;
    const int c0 = ncol & 255;
    const int tid = threadIdx.x;
    const int tx = tid & 15, ty = tid >> 4;
    const int lr = tid >> 2;                     // A-load row 0..63
    const int lk4 = (tid & 3) * 4;               // A-load k offset
    const int bx = tid & 63;
    float acc[4][4] = {};
    for (int k0 = 0; k0 < 256; k0 += 16) {
        float4 av = *(const float4*)(A + (size_t)(m0 + lr)*CS + k0 + lk4);
        As[lk4+0][lr] = av.x; As[lk4+1][lr] = av.y;
        As[lk4+2][lr] = av.z; As[lk4+3][lr] = av.w;
        #pragma unroll
        for (int i = 0; i < 4; i++) {
            int kk = (tid >> 6) + i*4;
            Bs[kk][bx] = W[(size_t)(k0 + kk)*CS + c0 + bx];
        }
        __syncthreads();
        #pragma unroll
        for (int kk = 0; kk < 16; kk++) {
            float4 a4 = *(const float4*)&As[kk][ty*4];
            float4 b4 = *(const float4*)&Bs[kk][tx*4];
            float av_[4] = {a4.x, a4.y, a4.z, a4.w};
            float bv_[4] = {b4.x, b4.y, b4.z, b4.w};
            #pragma unroll
            for (int i = 0; i < 4; i++)
                #pragma unroll
                for (int j = 0; j < 4; j++)
                    acc[i][j] += av_[i] * bv_[j];
        }
        __syncthreads();
    }
    #pragma unroll
    for (int i = 0; i < 4; i++) {
        int m = m0 + ty*4 + i;
        int ss = m >> 8, rr = m & 255;
        #pragma unroll
        for (int j = 0; j < 4; j++) {
            int lc = c0 + tx*4 + j;              // col within segment, 0..255
            float val = acc[i][j];
            if (seg == 0) {
                int h = lc >> 5, d = lc & 31;
                qo[(((size_t)ss*HEADS + h)*RDIM + rr)*DH + d] = val * 0.17677669529663687f;
            } else if (seg == 1) {
                int h = lc >> 5, d = lc & 31;
                ko[(((size_t)ss*HEADS + h)*RDIM + rr)*DH + d] = val;
            } else if (seg == 2) {
                int h = lc >> 5, d = lc & 31;
                vo[(((size_t)ss*HEADS + h)*RDIM + rr)*DH + d] = val;
            } else {
                float x = val + bg[lc];
                go[(size_t)m*CS + lc] = 1.f / (1.f + expf(-x));
            }
        }
    }
}

// ------------- attention: MFMA flash, one block per (s,h), 4 waves -------
// Each wave owns 64 q-rows. D=32 = one 16x16x32 bf16 MFMA K-step.
// K_lds [256][40] bf16 (pad->2-way), Vt_lds [32][264] bf16, P bounced
// through per-wave LDS [64][72] to relayout C->A frags.
__global__ __launch_bounds__(256, 2) void attn_kernel(const float* __restrict__ q,
        const float* __restrict__ k, const float* __restrict__ v,
        const float* __restrict__ pb, const float* __restrict__ mask,
        float* __restrict__ o) {
    __shared__ unsigned short Klds[256][40];
    __shared__ unsigned short Vtlds[32][264];
    __shared__ unsigned short Plds[4][64][72];
    __shared__ float masklds[256];

    const int sh = blockIdx.x;                   // s*8 + h
    const int ss = sh >> 3, h = sh & 7;
    const int tid = threadIdx.x;
    const int lane = tid & 63, wid = tid >> 6;
    const int ln15 = lane & 15, g = lane >> 4;   // g in 0..3
    const int q0 = wid * 64;

    const float* kp = k + (size_t)sh * 8192;
    const float* vp = v + (size_t)sh * 8192;
    // ---- stage K (bf16) and V^T (bf16) to LDS ----
    #pragma unroll
    for (int i = 0; i < 8; i++) {
        int idx = tid + i*256;                   // float4 units, 0..2047
        int row = idx >> 3, col = (idx & 7) * 4; // row: k-index, col: d
        float4 kv = ((const float4*)kp)[idx];
        float4 vv = ((const float4*)vp)[idx];
        ushort4 kq; kq.x=f2bf(kv.x); kq.y=f2bf(kv.y); kq.z=f2bf(kv.z); kq.w=f2bf(kv.w);
        *(ushort4*)&Klds[row][col] = kq;
        Vtlds[col+0][row] = f2bf(vv.x);
        Vtlds[col+1][row] = f2bf(vv.y);
        Vtlds[col+2][row] = f2bf(vv.z);
        Vtlds[col+3][row] = f2bf(vv.w);
    }
    masklds[tid] = 1e9f * (mask[(size_t)ss*RDIM + tid] - 1.f);

    // ---- Q A-frags in registers (row = ln15, k8 = g*8) ----
    short8_t qf[4];
    {
        const float* qp = q + (size_t)sh * 8192;
        #pragma unroll
        for (int qi = 0; qi < 4; qi++) {
            const float* qrow = qp + (size_t)(q0 + qi*16 + ln15)*DH + g*8;
            float4 a0 = *(const float4*)qrow;
            float4 a1 = *(const float4*)(qrow + 4);
            short8_t f;
            f[0]=(short)f2bf(a0.x); f[1]=(short)f2bf(a0.y);
            f[2]=(short)f2bf(a0.z); f[3]=(short)f2bf(a0.w);
            f[4]=(short)f2bf(a1.x); f[5]=(short)f2bf(a1.y);
            f[6]=(short)f2bf(a1.z); f[7]=(short)f2bf(a1.w);
            qf[qi] = f;
        }
    }
    __syncthreads();

    const float* pbh = pb + (size_t)h * ZROWS;
    float m_s[4][4], l_s[4][4];
    #pragma unroll
    for (int qi = 0; qi < 4; qi++)
        #pragma unroll
        for (int r = 0; r < 4; r++) { m_s[qi][r] = -INFINITY; l_s[qi][r] = 0.f; }
    f32x4 oa[4][2];
    #pragma unroll
    for (int qi = 0; qi < 4; qi++)
        #pragma unroll
        for (int dj = 0; dj < 2; dj++) oa[qi][dj] = (f32x4){0.f,0.f,0.f,0.f};

    for (int c = 0; c < 4; c++) {
        const int k0 = c * 64;
        // K B-frags (col = ln15 = k, k8 = g*8 over d)
        short8_t kf[4];
        #pragma unroll
        for (int kj = 0; kj < 4; kj++)
            kf[kj] = *(const short8_t*)&Klds[k0 + kj*16 + ln15][g*8];
        // S = Q @ K^T  (one MFMA per 16x16 tile, K-dim = 32 = D)
        f32x4 sc[4][4];
        #pragma unroll
        for (int qi = 0; qi < 4; qi++)
            #pragma unroll
            for (int kj = 0; kj < 4; kj++)
                sc[qi][kj] = __builtin_amdgcn_mfma_f32_16x16x32_bf16(
                                 qf[qi], kf[kj], (f32x4){0.f,0.f,0.f,0.f}, 0, 0, 0);
        // bias add: mask (k only) + pair bias pb[h][q][k]
        float mk[4];
        #pragma unroll
        for (int kj = 0; kj < 4; kj++) mk[kj] = masklds[k0 + kj*16 + ln15];
        #pragma unroll
        for (int qi = 0; qi < 4; qi++) {
            const float* pbp = pbh + (size_t)(q0 + qi*16 + g*4)*RDIM + k0 + ln15;
            #pragma unroll
            for (int kj = 0; kj < 4; kj++)
                #pragma unroll
                for (int r = 0; r < 4; r++)
                    sc[qi][kj][r] += mk[kj] + pbp[(size_t)r*RDIM + kj*16];
        }
        // online softmax per q-row (row r lives in the same lane as oa reg r)
        float corr[4][4];
        #pragma unroll
        for (int qi = 0; qi < 4; qi++) {
            #pragma unroll
            for (int r = 0; r < 4; r++) {
                float t = fmaxf(fmaxf(sc[qi][0][r], sc[qi][1][r]),
                                fmaxf(sc[qi][2][r], sc[qi][3][r]));
                t = fmaxf(t, __shfl_xor(t, 1, 64));
                t = fmaxf(t, __shfl_xor(t, 2, 64));
                t = fmaxf(t, __shfl_xor(t, 4, 64));
                t = fmaxf(t, __shfl_xor(t, 8, 64));
                float mo = m_s[qi][r];
                float mn = fmaxf(mo, t);
                float cr = exp2f((mo - mn) * LOG2E);
                m_s[qi][r] = mn; corr[qi][r] = cr;
                float rs = 0.f;
                #pragma unroll
                for (int kj = 0; kj < 4; kj++) {
                    float p = exp2f((sc[qi][kj][r] - mn) * LOG2E);
                    sc[qi][kj][r] = p;
                    rs += p;
                }
                rs += __shfl_xor(rs, 1, 64);
                rs += __shfl_xor(rs, 2, 64);
                rs += __shfl_xor(rs, 4, 64);
                rs += __shfl_xor(rs, 8, 64);
                l_s[qi][r] = l_s[qi][r]*cr + rs;
            }
        }
        // rescale O accumulators
        #pragma unroll
        for (int qi = 0; qi < 4; qi++)
            #pragma unroll
            for (int dj = 0; dj < 2; dj++)
                #pragma unroll
                for (int r = 0; r < 4; r++)
                    oa[qi][dj][r] *= corr[qi][r];
        // P -> bf16 via per-wave LDS bounce (C-layout -> A-frag relayout)
        #pragma unroll
        for (int qi = 0; qi < 4; qi++)
            #pragma unroll
            for (int kj = 0; kj < 4; kj++)
                #pragma unroll
                for (int r = 0; r < 4; r++)
                    Plds[wid][qi*16 + g*4 + r][kj*16 + ln15] = f2bf(sc[qi][kj][r]);
        // O += P @ V
        #pragma unroll
        for (int ks = 0; ks < 2; ks++) {
            short8_t pa[4], vf[2];
            #pragma unroll
            for (int qi = 0; qi < 4; qi++)
                pa[qi] = *(const short8_t*)&Plds[wid][qi*16 + ln15][ks*32 + g*8];
            #pragma unroll
            for (int dj = 0; dj < 2; dj++)
                vf[dj] = *(const short8_t*)&Vtlds[dj*16 + ln15][k0 + ks*32 + g*8];
            #pragma unroll
            for (int qi = 0; qi < 4; qi++)
                #pragma unroll
                for (int dj = 0; dj < 2; dj++)
                    oa[qi][dj] = __builtin_amdgcn_mfma_f32_16x16x32_bf16(
                                     pa[qi], vf[dj], oa[qi][dj], 0, 0, 0);
        }
    }
    // epilogue: normalize and store (o layout [s][q][h*32+d])
    #pragma unroll
    for (int qi = 0; qi < 4; qi++) {
        #pragma unroll
        for (int r = 0; r < 4; r++) {
            int qrow = q0 + qi*16 + g*4 + r;
            float inv = 1.f / l_s[qi][r];
            #pragma unroll
            for (int dj = 0; dj < 2; dj++)
                o[((size_t)ss*RDIM + qrow)*CS + h*DH + dj*16 + ln15] = oa[qi][dj][r] * inv;
        }
    }
}

// ------------- output projection: out = (o .* g) @ wo + bo ---------------
__global__ __launch_bounds__(256) void outproj_kernel(const float* __restrict__ o,
        const float* __restrict__ g, const float* __restrict__ wo,
        const float* __restrict__ bo, float* __restrict__ out) {
    __shared__ float As[16][64];
    __shared__ float Bs[16][64];
    const int m0 = blockIdx.x * 64;
    const int c0 = blockIdx.y * 64;              // 0..255
    const int tid = threadIdx.x;
    const int tx = tid & 15, ty = tid >> 4;
    const int lr = tid >> 2;
    const int lk4 = (tid & 3) * 4;
    const int bx = tid & 63;
    float acc[4][4] = {};
    for (int k0 = 0; k0 < 256; k0 += 16) {
        float4 av = *(const float4*)(o + (size_t)(m0 + lr)*CS + k0 + lk4);
        float4 gv = *(const float4*)(g + (size_t)(m0 + lr)*CS + k0 + lk4);
        As[lk4+0][lr] = av.x*gv.x; As[lk4+1][lr] = av.y*gv.y;
        As[lk4+2][lr] = av.z*gv.z; As[lk4+3][lr] = av.w*gv.w;
        #pragma unroll
        for (int i = 0; i < 4; i++) {
            int kk = (tid >> 6) + i*4;
            Bs[kk][bx] = wo[(size_t)(k0 + kk)*CS + c0 + bx];
        }
        __syncthreads();
        #pragma unroll
        for (int kk = 0; kk < 16; kk++) {
            float4 a4 = *(const float4*)&As[kk][ty*4];
            float4 b4 = *(const float4*)&Bs[kk][tx*4];
            float av_[4] = {a4.x, a4.y, a4.z, a4.w};
            float bv_[4] = {b4.x, b4.y, b4.z, b4.w};
            #pragma unroll
            for (int i = 0; i < 4; i++)
                #pragma unroll
                for (int j = 0; j < 4; j++)
                    acc[i][j] += av_[i] * bv_[j];
        }
        __syncthreads();
    }
    #pragma unroll
    for (int i = 0; i < 4; i++) {
        int m = m0 + ty*4 + i;
        #pragma unroll
        for (int j = 0; j < 4; j++) {
            int c = c0 + tx*4 + j;
            out[(size_t)m*CS + c] = acc[i][j] + bo[c];
        }
    }
}

extern "C" void kernel_launch(void* const* d_in, const int* in_sizes, int n_in,
                              void* d_out, int out_size, void* d_ws, size_t ws_size,
                              hipStream_t stream) {
    const float* s      = (const float*)d_in[0];
    const float* z      = (const float*)d_in[1];
    const float* mask   = (const float*)d_in[2];
    const float* ln_s_w = (const float*)d_in[3];
    const float* ln_s_b = (const float*)d_in[4];
    const float* ln_z_w = (const float*)d_in[5];
    const float* ln_z_b = (const float*)d_in[6];
    const float* w_z    = (const float*)d_in[7];
    const float* w_q    = (const float*)d_in[8];
    const float* w_k    = (const float*)d_in[9];
    const float* w_v    = (const float*)d_in[10];
    const float* w_g    = (const float*)d_in[11];
    const float* b_g    = (const float*)d_in[12];
    const float* w_o    = (const float*)d_in[13];
    const float* b_o    = (const float*)d_in[14];
    float* out = (float*)d_out;
    float* ws  = (float*)d_ws;

    float* sn  = ws;                       // 8388608 (aliased by o; sn dead after qkvg)
    float* o   = ws;
    float* pbv = ws + 8388608;             // 524288  [h][q][k]
    float* qb  = pbv + 524288;             // 8388608 [S,H,R,D]
    float* kb  = qb + 8388608;             // 8388608
    float* vb  = kb + 8388608;             // 8388608
    float* gb  = vb + 8388608;             // 8388608
    // total = 42467328 floats = 169.9 MB of d_ws

    ln_s_kernel<<<MROWS/4, 256, 0, stream>>>(s, ln_s_w, ln_s_b, sn);
    ln_z_pb_kernel<<<ZROWS/4, 256, 0, stream>>>(z, ln_z_w, ln_z_b, w_z, pbv);
    qkvg_kernel<<<dim3(MROWS/64, 16), 256, 0, stream>>>(sn, w_q, w_k, w_v, w_g, b_g,
                                                        qb, kb, vb, gb);
    attn_kernel<<<SDIM*HEADS, 256, 0, stream>>>(qb, kb, vb, pbv, mask, o);
    outproj_kernel<<<dim3(MROWS/64, 4), 256, 0, stream>>>(o, gb, w_o, b_o, out);
}

// Round 7
// 238.995 us; speedup vs baseline: 2.6618x; 2.0312x over previous
//
#include <hip/hip_runtime.h>
#include <math.h>

#define CS 256
#define CZ 128
#define HEADS 8
#define DH 32
#define SDIM 128
#define RDIM 256
#define MROWS (SDIM*RDIM)   // 32768
#define ZROWS (RDIM*RDIM)   // 65536
#define EPSF 1e-5f
#define LOG2E 1.44269504088896340736f

typedef __attribute__((ext_vector_type(8))) short short8_t;   // 8 bf16 (4 VGPRs)
typedef __attribute__((ext_vector_type(4))) float f32x4;

__device__ __forceinline__ float waveReduceSum(float v) {
    #pragma unroll
    for (int off = 32; off > 0; off >>= 1) v += __shfl_xor(v, off, 64);
    return v;
}

__device__ __forceinline__ unsigned short f2bf(float f) {
    unsigned u = __float_as_uint(f);
    unsigned r = (u + 0x7fffu + ((u >> 16) & 1u)) >> 16;   // RNE
    return (unsigned short)r;
}

__device__ __forceinline__ float bf2f(unsigned short u) {
    return __uint_as_float(((unsigned)u) << 16);
}

// ---------------- LayerNorm of s: one wave per row of 256, bf16 out ------
__global__ __launch_bounds__(256) void ln_s_kernel(const float* __restrict__ s,
        const float* __restrict__ w, const float* __restrict__ b,
        unsigned short* __restrict__ snb) {
    int wid = threadIdx.x >> 6;
    int lane = threadIdx.x & 63;
    int row = blockIdx.x * 4 + wid;              // < 32768
    const float4 v = ((const float4*)(s + (size_t)row * CS))[lane];
    float sum = waveReduceSum(v.x + v.y + v.z + v.w);
    float sq  = waveReduceSum(v.x*v.x + v.y*v.y + v.z*v.z + v.w*v.w);
    float mean = sum * (1.f/CS);
    float var  = sq * (1.f/CS) - mean*mean;
    float rstd = rsqrtf(var + EPSF);
    const float4 wv = ((const float4*)w)[lane];
    const float4 bv = ((const float4*)b)[lane];
    ushort4 o;
    o.x = f2bf((v.x-mean)*rstd*wv.x + bv.x);
    o.y = f2bf((v.y-mean)*rstd*wv.y + bv.y);
    o.z = f2bf((v.z-mean)*rstd*wv.z + bv.z);
    o.w = f2bf((v.w-mean)*rstd*wv.w + bv.w);
    ((ushort4*)(snb + (size_t)row * CS))[lane] = o;
}

// ------- LayerNorm of z + pair bias: one wave per (q,k) row of 128 -------
// writes pb[h][q][k]
__global__ __launch_bounds__(256) void ln_z_pb_kernel(const float* __restrict__ z,
        const float* __restrict__ w, const float* __restrict__ b,
        const float* __restrict__ wz, float* __restrict__ pb) {
    int wid = threadIdx.x >> 6;
    int lane = threadIdx.x & 63;
    int row = blockIdx.x * 4 + wid;              // row = q*256 + k, < 65536
    const float2 v = ((const float2*)(z + (size_t)row * CZ))[lane];
    float sum = waveReduceSum(v.x + v.y);
    float sq  = waveReduceSum(v.x*v.x + v.y*v.y);
    float mean = sum * (1.f/CZ);
    float var  = sq * (1.f/CZ) - mean*mean;
    float rstd = rsqrtf(var + EPSF);
    const float2 wv = ((const float2*)w)[lane];
    const float2 bv = ((const float2*)b)[lane];
    float n0 = (v.x-mean)*rstd*wv.x + bv.x;
    float n1 = (v.y-mean)*rstd*wv.y + bv.y;
    const float* wz0 = wz + (size_t)(lane*2) * HEADS;   // wz: [128][8]
    float ph[8];
    #pragma unroll
    for (int h = 0; h < 8; h++) ph[h] = n0*wz0[h] + n1*wz0[HEADS + h];
    #pragma unroll
    for (int h = 0; h < 8; h++) ph[h] = waveReduceSum(ph[h]);
    if (lane == 0) {
        #pragma unroll
        for (int h = 0; h < 8; h++)
            pb[(size_t)h*ZROWS + row] = ph[h];   // [h][q][k]
    }
}

// ----- weight convert: w[k][n] fp32 -> wt[n][k] bf16 (n-major for B-frag) -
__global__ __launch_bounds__(256) void wconv_kernel(const float* __restrict__ wq,
        const float* __restrict__ wk, const float* __restrict__ wv,
        const float* __restrict__ wg, const float* __restrict__ wo,
        unsigned short* __restrict__ wtb, unsigned short* __restrict__ wot) {
    __shared__ float T[64][65];
    const int wi = blockIdx.z;
    const float* W = (wi==0)?wq:(wi==1)?wk:(wi==2)?wv:(wi==3)?wg:wo;
    unsigned short* O = (wi<4) ? (wtb + (size_t)wi*65536) : wot;
    const int bk = blockIdx.x * 64, bn = blockIdx.y * 64;
    const int tx = threadIdx.x & 63, tg = threadIdx.x >> 6;
    #pragma unroll
    for (int i = 0; i < 16; i++) {
        int r = tg*16 + i;
        T[r][tx] = W[(size_t)(bk+r)*256 + bn + tx];
    }
    __syncthreads();
    #pragma unroll
    for (int i = 0; i < 16; i++) {
        int r = tg*16 + i;
        O[(size_t)(bn+r)*256 + bk + tx] = f2bf(T[tx][r]);
    }
}

// ------------- QKVG projection GEMM (MFMA): M=32768, K=256, N=1024 -------
// A = snb [M][256] bf16; B = wtb [4][256][256] bf16 n-major.
// 128x128 tile, BK=64, 4 waves 2x2, each wave 64x64 (4x4 16x16 frags).
// q/k/v written [S,H,R,D] bf16 (q pre-scaled); g = sigmoid(.+bg) [M][256] bf16.
__global__ __launch_bounds__(256, 2) void qkvg_kernel(
        const unsigned short* __restrict__ snb,
        const unsigned short* __restrict__ wtb,
        const float* __restrict__ bg,
        unsigned short* __restrict__ qo, unsigned short* __restrict__ ko,
        unsigned short* __restrict__ vo, unsigned short* __restrict__ go) {
    __shared__ alignas(16) unsigned short As[128][72];   // pad 64->72: 2-way only
    __shared__ alignas(16) unsigned short Bs[128][72];
    const int m0 = blockIdx.x * 128;
    const int n0 = blockIdx.y * 128;             // 0..896
    const int seg = n0 >> 8;
    const int nseg = n0 & 255;                   // 0 or 128
    const unsigned short* wt = wtb + (size_t)seg * 65536;
    const int tid = threadIdx.x;
    const int lane = tid & 63, wid = tid >> 6;
    const int ln15 = lane & 15, g = lane >> 4;
    const int wr = wid >> 1, wc = wid & 1;
    f32x4 acc[4][4];
    #pragma unroll
    for (int i = 0; i < 4; i++)
        #pragma unroll
        for (int j = 0; j < 4; j++) acc[i][j] = (f32x4){0.f,0.f,0.f,0.f};

    for (int k0 = 0; k0 < 256; k0 += 64) {
        #pragma unroll
        for (int c = 0; c < 4; c++) {
            int L = tid + c*256;                 // 0..1023 chunks of 8 bf16
            int row = L >> 3, kc = (L & 7) * 8;
            *(short8_t*)&As[row][kc] =
                *(const short8_t*)&snb[(size_t)(m0+row)*256 + k0 + kc];
            *(short8_t*)&Bs[row][kc] =
                *(const short8_t*)&wt[(size_t)(nseg+row)*256 + k0 + kc];
        }
        __syncthreads();
        #pragma unroll
        for (int kk = 0; kk < 64; kk += 32) {
            short8_t a[4], b[4];
            #pragma unroll
            for (int i = 0; i < 4; i++) {
                a[i] = *(const short8_t*)&As[wr*64 + i*16 + ln15][kk + g*8];
                b[i] = *(const short8_t*)&Bs[wc*64 + i*16 + ln15][kk + g*8];
            }
            #pragma unroll
            for (int i = 0; i < 4; i++)
                #pragma unroll
                for (int j = 0; j < 4; j++)
                    acc[i][j] = __builtin_amdgcn_mfma_f32_16x16x32_bf16(
                                    a[i], b[j], acc[i][j], 0, 0, 0);
        }
        __syncthreads();
    }
    #pragma unroll
    for (int i = 0; i < 4; i++) {
        #pragma unroll
        for (int r = 0; r < 4; r++) {
            int m = m0 + wr*64 + i*16 + g*4 + r;
            int ss = m >> 8, rr = m & 255;
            #pragma unroll
            for (int j = 0; j < 4; j++) {
                int col = n0 + wc*64 + j*16 + ln15;
                int lc = col & 255;
                int h = lc >> 5, d = lc & 31;
                float val = acc[i][j][r];
                size_t qidx = (((size_t)ss*HEADS + h)*RDIM + rr)*DH + d;
                if (seg == 0)      qo[qidx] = f2bf(val * 0.17677669529663687f);
                else if (seg == 1) ko[qidx] = f2bf(val);
                else if (seg == 2) vo[qidx] = f2bf(val);
                else {
                    float x = val + bg[lc];
                    go[(size_t)m*CS + lc] = f2bf(1.f / (1.f + expf(-x)));
                }
            }
        }
    }
}

// ------------- attention: MFMA flash, one block per (s,h), 4 waves -------
// bf16 q/k/v in, bf16 o out ([s][q][256]).
__global__ __launch_bounds__(256, 2) void attn_kernel(
        const unsigned short* __restrict__ q, const unsigned short* __restrict__ k,
        const unsigned short* __restrict__ v, const float* __restrict__ pb,
        const float* __restrict__ mask, unsigned short* __restrict__ o) {
    __shared__ unsigned short Klds[256][40];
    __shared__ unsigned short Vtlds[32][264];
    __shared__ unsigned short Plds[4][64][72];
    __shared__ float masklds[256];

    const int sh = blockIdx.x;                   // s*8 + h
    const int ss = sh >> 3, h = sh & 7;
    const int tid = threadIdx.x;
    const int lane = tid & 63, wid = tid >> 6;
    const int ln15 = lane & 15, g = lane >> 4;   // g in 0..3
    const int q0 = wid * 64;

    const unsigned short* kp = k + (size_t)sh * 8192;
    const unsigned short* vp = v + (size_t)sh * 8192;
    // ---- stage K and V^T to LDS (bf16 passthrough) ----
    #pragma unroll
    for (int i = 0; i < 4; i++) {
        int idx = tid + i*256;                   // chunk of 8 bf16, 0..1023
        int row = idx >> 2, col = (idx & 3) * 8; // row: k-index, col: d
        short8_t kv8 = *(const short8_t*)&kp[(size_t)row*DH + col];
        short8_t vv8 = *(const short8_t*)&vp[(size_t)row*DH + col];
        *(short8_t*)&Klds[row][col] = kv8;
        #pragma unroll
        for (int e = 0; e < 8; e++)
            Vtlds[col+e][row] = (unsigned short)vv8[e];
    }
    masklds[tid] = 1e9f * (mask[(size_t)ss*RDIM + tid] - 1.f);

    // ---- Q A-frags: direct global short8 loads ----
    short8_t qf[4];
    {
        const unsigned short* qp = q + (size_t)sh * 8192;
        #pragma unroll
        for (int qi = 0; qi < 4; qi++)
            qf[qi] = *(const short8_t*)&qp[(size_t)(q0 + qi*16 + ln15)*DH + g*8];
    }
    __syncthreads();

    const float* pbh = pb + (size_t)h * ZROWS;
    float m_s[4][4], l_s[4][4];
    #pragma unroll
    for (int qi = 0; qi < 4; qi++)
        #pragma unroll
        for (int r = 0; r < 4; r++) { m_s[qi][r] = -INFINITY; l_s[qi][r] = 0.f; }
    f32x4 oa[4][2];
    #pragma unroll
    for (int qi = 0; qi < 4; qi++)
        #pragma unroll
        for (int dj = 0; dj < 2; dj++) oa[qi][dj] = (f32x4){0.f,0.f,0.f,0.f};

    for (int c = 0; c < 4; c++) {
        const int k0 = c * 64;
        short8_t kf[4];
        #pragma unroll
        for (int kj = 0; kj < 4; kj++)
            kf[kj] = *(const short8_t*)&Klds[k0 + kj*16 + ln15][g*8];
        f32x4 sc[4][4];
        #pragma unroll
        for (int qi = 0; qi < 4; qi++)
            #pragma unroll
            for (int kj = 0; kj < 4; kj++)
                sc[qi][kj] = __builtin_amdgcn_mfma_f32_16x16x32_bf16(
                                 qf[qi], kf[kj], (f32x4){0.f,0.f,0.f,0.f}, 0, 0, 0);
        float mk[4];
        #pragma unroll
        for (int kj = 0; kj < 4; kj++) mk[kj] = masklds[k0 + kj*16 + ln15];
        #pragma unroll
        for (int qi = 0; qi < 4; qi++) {
            const float* pbp = pbh + (size_t)(q0 + qi*16 + g*4)*RDIM + k0 + ln15;
            #pragma unroll
            for (int kj = 0; kj < 4; kj++)
                #pragma unroll
                for (int r = 0; r < 4; r++)
                    sc[qi][kj][r] += mk[kj] + pbp[(size_t)r*RDIM + kj*16];
        }
        float corr[4][4];
        #pragma unroll
        for (int qi = 0; qi < 4; qi++) {
            #pragma unroll
            for (int r = 0; r < 4; r++) {
                float t = fmaxf(fmaxf(sc[qi][0][r], sc[qi][1][r]),
                                fmaxf(sc[qi][2][r], sc[qi][3][r]));
                t = fmaxf(t, __shfl_xor(t, 1, 64));
                t = fmaxf(t, __shfl_xor(t, 2, 64));
                t = fmaxf(t, __shfl_xor(t, 4, 64));
                t = fmaxf(t, __shfl_xor(t, 8, 64));
                float mo = m_s[qi][r];
                float mn = fmaxf(mo, t);
                float cr = exp2f((mo - mn) * LOG2E);
                m_s[qi][r] = mn; corr[qi][r] = cr;
                float rs = 0.f;
                #pragma unroll
                for (int kj = 0; kj < 4; kj++) {
                    float p = exp2f((sc[qi][kj][r] - mn) * LOG2E);
                    sc[qi][kj][r] = p;
                    rs += p;
                }
                rs += __shfl_xor(rs, 1, 64);
                rs += __shfl_xor(rs, 2, 64);
                rs += __shfl_xor(rs, 4, 64);
                rs += __shfl_xor(rs, 8, 64);
                l_s[qi][r] = l_s[qi][r]*cr + rs;
            }
        }
        #pragma unroll
        for (int qi = 0; qi < 4; qi++)
            #pragma unroll
            for (int dj = 0; dj < 2; dj++)
                #pragma unroll
                for (int r = 0; r < 4; r++)
                    oa[qi][dj][r] *= corr[qi][r];
        #pragma unroll
        for (int qi = 0; qi < 4; qi++)
            #pragma unroll
            for (int kj = 0; kj < 4; kj++)
                #pragma unroll
                for (int r = 0; r < 4; r++)
                    Plds[wid][qi*16 + g*4 + r][kj*16 + ln15] = f2bf(sc[qi][kj][r]);
        #pragma unroll
        for (int ks = 0; ks < 2; ks++) {
            short8_t pa[4], vf[2];
            #pragma unroll
            for (int qi = 0; qi < 4; qi++)
                pa[qi] = *(const short8_t*)&Plds[wid][qi*16 + ln15][ks*32 + g*8];
            #pragma unroll
            for (int dj = 0; dj < 2; dj++)
                vf[dj] = *(const short8_t*)&Vtlds[dj*16 + ln15][k0 + ks*32 + g*8];
            #pragma unroll
            for (int qi = 0; qi < 4; qi++)
                #pragma unroll
                for (int dj = 0; dj < 2; dj++)
                    oa[qi][dj] = __builtin_amdgcn_mfma_f32_16x16x32_bf16(
                                     pa[qi], vf[dj], oa[qi][dj], 0, 0, 0);
        }
    }
    #pragma unroll
    for (int qi = 0; qi < 4; qi++) {
        #pragma unroll
        for (int r = 0; r < 4; r++) {
            int qrow = q0 + qi*16 + g*4 + r;
            float inv = 1.f / l_s[qi][r];
            #pragma unroll
            for (int dj = 0; dj < 2; dj++)
                o[((size_t)ss*RDIM + qrow)*CS + h*DH + dj*16 + ln15] =
                    f2bf(oa[qi][dj][r] * inv);
        }
    }
}

// ------------- output projection (MFMA): out = (o .* g) @ wo + bo --------
// A staged as bf16(o*g); B = wot [256][256] bf16 n-major. M=32768,K=256,N=256.
__global__ __launch_bounds__(256, 2) void outproj_kernel(
        const unsigned short* __restrict__ ob, const unsigned short* __restrict__ gb,
        const unsigned short* __restrict__ wot, const float* __restrict__ bo,
        float* __restrict__ out) {
    __shared__ alignas(16) unsigned short As[128][72];
    __shared__ alignas(16) unsigned short Bs[128][72];
    const int m0 = blockIdx.x * 128;
    const int n0 = blockIdx.y * 128;             // 0 or 128
    const int tid = threadIdx.x;
    const int lane = tid & 63, wid = tid >> 6;
    const int ln15 = lane & 15, g = lane >> 4;
    const int wr = wid >> 1, wc = wid & 1;
    f32x4 acc[4][4];
    #pragma unroll
    for (int i = 0; i < 4; i++)
        #pragma unroll
        for (int j = 0; j < 4; j++) acc[i][j] = (f32x4){0.f,0.f,0.f,0.f};

    for (int k0 = 0; k0 < 256; k0 += 64) {
        #pragma unroll
        for (int c = 0; c < 4; c++) {
            int L = tid + c*256;
            int row = L >> 3, kc = (L & 7) * 8;
            short8_t ov = *(const short8_t*)&ob[(size_t)(m0+row)*256 + k0 + kc];
            short8_t gv = *(const short8_t*)&gb[(size_t)(m0+row)*256 + k0 + kc];
            short8_t pr;
            #pragma unroll
            for (int e = 0; e < 8; e++)
                pr[e] = (short)f2bf(bf2f((unsigned short)ov[e]) *
                                    bf2f((unsigned short)gv[e]));
            *(short8_t*)&As[row][kc] = pr;
            *(short8_t*)&Bs[row][kc] =
                *(const short8_t*)&wot[(size_t)(n0+row)*256 + k0 + kc];
        }
        __syncthreads();
        #pragma unroll
        for (int kk = 0; kk < 64; kk += 32) {
            short8_t a[4], b[4];
            #pragma unroll
            for (int i = 0; i < 4; i++) {
                a[i] = *(const short8_t*)&As[wr*64 + i*16 + ln15][kk + g*8];
                b[i] = *(const short8_t*)&Bs[wc*64 + i*16 + ln15][kk + g*8];
            }
            #pragma unroll
            for (int i = 0; i < 4; i++)
                #pragma unroll
                for (int j = 0; j < 4; j++)
                    acc[i][j] = __builtin_amdgcn_mfma_f32_16x16x32_bf16(
                                    a[i], b[j], acc[i][j], 0, 0, 0);
        }
        __syncthreads();
    }
    #pragma unroll
    for (int i = 0; i < 4; i++) {
        #pragma unroll
        for (int r = 0; r < 4; r++) {
            int m = m0 + wr*64 + i*16 + g*4 + r;
            #pragma unroll
            for (int j = 0; j < 4; j++) {
                int col = n0 + wc*64 + j*16 + ln15;
                out[(size_t)m*CS + col] = acc[i][j][r] + bo[col];
            }
        }
    }
}

extern "C" void kernel_launch(void* const* d_in, const int* in_sizes, int n_in,
                              void* d_out, int out_size, void* d_ws, size_t ws_size,
                              hipStream_t stream) {
    const float* s      = (const float*)d_in[0];
    const float* z      = (const float*)d_in[1];
    const float* mask   = (const float*)d_in[2];
    const float* ln_s_w = (const float*)d_in[3];
    const float* ln_s_b = (const float*)d_in[4];
    const float* ln_z_w = (const float*)d_in[5];
    const float* ln_z_b = (const float*)d_in[6];
    const float* w_z    = (const float*)d_in[7];
    const float* w_q    = (const float*)d_in[8];
    const float* w_k    = (const float*)d_in[9];
    const float* w_v    = (const float*)d_in[10];
    const float* w_g    = (const float*)d_in[11];
    const float* b_g    = (const float*)d_in[12];
    const float* w_o    = (const float*)d_in[13];
    const float* b_o    = (const float*)d_in[14];
    float* out = (float*)d_out;
    float* ws  = (float*)d_ws;

    // Workspace layout (float units; bf16 buffers cast):
    unsigned short* snb = (unsigned short*)ws;                    // 8388608 shorts
    unsigned short* wtb = (unsigned short*)(ws + 4194304);        // 262144 shorts
    unsigned short* wot = (unsigned short*)(ws + 4194304+131072); // 65536 shorts
    float* pbv = ws + 4194304 + 131072 + 32768;                   // 524288 floats
    unsigned short* qb  = (unsigned short*)(pbv + 524288);        // 8388608 shorts each
    unsigned short* kb  = qb + 8388608;
    unsigned short* vb  = kb + 8388608;
    unsigned short* gbuf= vb + 8388608;
    unsigned short* obuf= gbuf + 8388608;
    // total = 25,853,952 floats = 103.4 MB

    ln_s_kernel<<<MROWS/4, 256, 0, stream>>>(s, ln_s_w, ln_s_b, snb);
    ln_z_pb_kernel<<<ZROWS/4, 256, 0, stream>>>(z, ln_z_w, ln_z_b, w_z, pbv);
    wconv_kernel<<<dim3(4,4,5), 256, 0, stream>>>(w_q, w_k, w_v, w_g, w_o, wtb, wot);
    qkvg_kernel<<<dim3(MROWS/128, 8), 256, 0, stream>>>(snb, wtb, b_g, qb, kb, vb, gbuf);
    attn_kernel<<<SDIM*HEADS, 256, 0, stream>>>(qb, kb, vb, pbv, mask, obuf);
    outproj_kernel<<<dim3(MROWS/128, 2), 256, 0, stream>>>(obuf, gbuf, wot, b_o, out);
}